// Round 13
// baseline (322.248 us; speedup 1.0000x reference)
//
#include <hip/hip_runtime.h>
#include <hip/hip_fp16.h>
#include <math.h>

#define N_NODES 100000
#define N_EDGES 1600000
#define NH 4
#define HD 16
#define NB 98             // ceil(100000/1024) scan blocks
#define AGG_GROUPS 25000  // N_NODES/4
#define AGG_BLOCKS 3125   // 8 groups per block exactly (no ragged tail)
#define SCAT4_BLOCKS 1563 // ceil(400000 threads / 256), 4 edges per thread
#define QKV_TILES 6250    // 100000/16 node-tiles
#define QKV_TPG 4         // tiles per wave
#define QKV_GROUPS 1563   // ceil(6250/4)
#define QKV_WAVES (2 * QKV_GROUPS)  // Q-groups + fused-KV-groups
#define OP_GROUPS 1563    // oproj wave-groups (4 tiles each)

typedef float fx4 __attribute__((ext_vector_type(4)));
typedef int   ix4 __attribute__((ext_vector_type(4)));
typedef _Float16 h8v __attribute__((ext_vector_type(8)));

// ---- CSR build -------------------------------------------------------------

// off[] must be zeroed (hipMemsetAsync) before this.
// Saves each edge's within-node arrival rank so scatter needs NO atomic.
__global__ void hist_kernel(const int* __restrict__ dst_idx, int* __restrict__ off,
                            int* __restrict__ rank) {
    int tid = blockIdx.x * blockDim.x + threadIdx.x;
    int base = tid * 4;
    if (base + 3 < N_EDGES) {
        int4 d = ((const int4*)dst_idx)[tid];  // cached: dst_idx reused by scatter
        int4 r;
        r.x = atomicAdd(&off[d.x], 1);
        r.y = atomicAdd(&off[d.y], 1);
        r.z = atomicAdd(&off[d.z], 1);
        r.w = atomicAdd(&off[d.w], 1);
        ((int4*)rank)[tid] = r;
    } else {
        for (int j = base; j < N_EDGES; j++)
            if (j < N_EDGES) rank[j] = atomicAdd(&off[dst_idx[j]], 1);
    }
}

// per-block sums of 1024-element chunks
__global__ void scanA_kernel(const int* __restrict__ off, int* __restrict__ bsum) {
    __shared__ int s[256];
    int t = threadIdx.x;
    int base = blockIdx.x * 1024 + t * 4;
    int v = 0;
#pragma unroll
    for (int j = 0; j < 4; j++) {
        int idx = base + j;
        if (idx < N_NODES) v += off[idx];
    }
    s[t] = v;
    __syncthreads();
    for (int o = 128; o > 0; o >>= 1) {
        if (t < o) s[t] += s[t + o];
        __syncthreads();
    }
    if (t == 0) bsum[blockIdx.x] = s[0];
}

// in-place exclusive scan of counts -> offsets (scanB folded in).
__global__ void scanC_kernel(int* __restrict__ off, const int* __restrict__ bsum) {
    __shared__ int sb[NB];
    __shared__ int s[256];
    int t = threadIdx.x;
    if (t < NB) sb[t] = bsum[t];
    __syncthreads();
    int pre = 0, tot = 0;
    int myb = (int)blockIdx.x;
    for (int b = 0; b < NB; b++) {
        int x = sb[b];
        if (b < myb) pre += x;
        tot += x;
    }
    int base = myb * 1024 + t * 4;
    int v[4];
    int tsum = 0;
#pragma unroll
    for (int j = 0; j < 4; j++) {
        int idx = base + j;
        v[j] = (idx < N_NODES) ? off[idx] : 0;
        tsum += v[j];
    }
    s[t] = tsum;
    __syncthreads();
    for (int o = 1; o < 256; o <<= 1) {
        int x = (t >= o) ? s[t - o] : 0;
        __syncthreads();
        s[t] += x;
        __syncthreads();
    }
    int excl = s[t] - tsum + pre;
#pragma unroll
    for (int j = 0; j < 4; j++) {
        int idx = base + j;
        if (idx < N_NODES) {
            off[idx] = excl;
            excl += v[j];
        }
    }
    if (myb == 0 && t == 0) off[N_NODES] = tot;
}

// scatter edges into dst-grouped order; ONE packed 16B record per edge:
// {src, bias(h0,h1) fp16x2, bias(h2,h3) fp16x2, pad}
// Atomic-free (rank precomputed in hist). PLAIN cached store for prec
// (R7: NT store pushed prec to HBM and cost agg ~10%).
// 4 edges per thread: 4 independent random stores in flight per thread
// (VALUBusy was 2.8% -> waves idled on a single store; raise store MLP).
__global__ void scatter_kernel(const int* __restrict__ src_idx,
                               const int* __restrict__ dst_idx,
                               const int* __restrict__ rank,
                               const float* __restrict__ edge_feat,
                               const float* __restrict__ We,
                               const float* __restrict__ be,
                               const int* __restrict__ off,
                               ix4* __restrict__ prec) {
    int tid = blockIdx.x * blockDim.x + threadIdx.x;
    int base = tid * 4;
    if (base + 3 >= N_EDGES) return;  // N_EDGES % 4 == 0: all-or-nothing
    int4 d4 = ((const int4*)dst_idx)[tid];
    int4 s4 = ((const int4*)src_idx)[tid];
    int4 r4 = ((const int4*)rank)[tid];
    int dv[4] = {d4.x, d4.y, d4.z, d4.w};
    int sv[4] = {s4.x, s4.y, s4.z, s4.w};
    int rv[4] = {r4.x, r4.y, r4.z, r4.w};
#pragma unroll
    for (int j = 0; j < 4; j++) {
        long e = base + j;
        const fx4* ep = (const fx4*)(edge_feat + e * 16);
        fx4 e0 = __builtin_nontemporal_load(ep);      // true streaming, 102 MB
        fx4 e1 = __builtin_nontemporal_load(ep + 1);
        fx4 e2 = __builtin_nontemporal_load(ep + 2);
        fx4 e3 = __builtin_nontemporal_load(ep + 3);
        int pos = off[dv[j]] + rv[j];
        float bp[4];
#pragma unroll
        for (int h = 0; h < NH; h++) {
            const float4* wp = (const float4*)(We + h * 16);
            float4 w0 = wp[0], w1 = wp[1], w2 = wp[2], w3 = wp[3];
            float acc = be[h];
            acc += e0[0] * w0.x + e0[1] * w0.y + e0[2] * w0.z + e0[3] * w0.w;
            acc += e1[0] * w1.x + e1[1] * w1.y + e1[2] * w1.z + e1[3] * w1.w;
            acc += e2[0] * w2.x + e2[1] * w2.y + e2[2] * w2.z + e2[3] * w2.w;
            acc += e3[0] * w3.x + e3[1] * w3.y + e3[2] * w3.z + e3[3] * w3.w;
            bp[h] = acc;
        }
        __half2 b01 = __halves2half2(__float2half_rn(bp[0]), __float2half_rn(bp[1]));
        __half2 b23 = __halves2half2(__float2half_rn(bp[2]), __float2half_rn(bp[3]));
        ix4 rec;
        rec.x = sv[j];
        rec.y = __builtin_bit_cast(int, b01);
        rec.z = __builtin_bit_cast(int, b23);
        rec.w = 0;
        prec[pos] = rec;
    }
}

// ---- QKV projections via MFMA (fp16 hi/lo split = fp32-accurate) -----------
// A-frag: row=lane&15, k=(lane>>4)*8+j (contiguous from row-major feat).
// B-frag: col=lane&15, same k (contiguous from row-major W: need W[col][k]).
// D: col=lane&15, row=(lane>>4)*4+r.  (verified R5-R12, absmax unchanged)
// Split precision: x = hi + lo (fp16); D = Ah*Bh + Al*Bh + Ah*Bl, fp32 acc.
// 4 tiles per wave (B packed ONCE per 4 tiles); K+V fused in one wave.
__device__ __forceinline__ void pack2(fx4 a, fx4 b, h8v& hi, h8v& lo) {
#pragma unroll
    for (int j = 0; j < 4; j++) {
        float xa = a[j], xb = b[j];
        _Float16 ha = (_Float16)xa, hb = (_Float16)xb;
        hi[j] = ha;
        hi[j + 4] = hb;
        lo[j] = (_Float16)(xa - (float)ha);
        lo[j + 4] = (_Float16)(xb - (float)hb);
    }
}

#define MFMA6(ACC, AH0, AL0, AH1, AL1, BH0, BL0, BH1, BL1)                      \
    ACC = __builtin_amdgcn_mfma_f32_16x16x32_f16(AH0, BH0, ACC, 0, 0, 0);       \
    ACC = __builtin_amdgcn_mfma_f32_16x16x32_f16(AL0, BH0, ACC, 0, 0, 0);       \
    ACC = __builtin_amdgcn_mfma_f32_16x16x32_f16(AH0, BL0, ACC, 0, 0, 0);       \
    ACC = __builtin_amdgcn_mfma_f32_16x16x32_f16(AH1, BH1, ACC, 0, 0, 0);       \
    ACC = __builtin_amdgcn_mfma_f32_16x16x32_f16(AL1, BH1, ACC, 0, 0, 0);       \
    ACC = __builtin_amdgcn_mfma_f32_16x16x32_f16(AH1, BL1, ACC, 0, 0, 0);

__global__ __launch_bounds__(256) void qkv_kernel(
    const float* __restrict__ dst_feat, const float* __restrict__ src_feat,
    const float* __restrict__ Wq, const float* __restrict__ Wk,
    const float* __restrict__ Wv,
    float* __restrict__ Q, __half* __restrict__ KVh) {
    int lane = threadIdx.x & 63;
    int wid = threadIdx.x >> 6;
    int wave = blockIdx.x * 4 + wid;
    if (wave >= QKV_WAVES) return;
    bool isQ = wave < QKV_GROUPS;
    int tg = isQ ? wave : wave - QKV_GROUPS;
    const float* F = isQ ? dst_feat : src_feat;
    int r16 = lane & 15;
    int kg = lane >> 4;
    h8v Ah0[QKV_TPG], Al0[QKV_TPG], Ah1[QKV_TPG], Al1[QKV_TPG];
    int tbase[QKV_TPG];
    bool live[QKV_TPG];
#pragma unroll
    for (int t = 0; t < QKV_TPG; t++) {
        int tile = tg * QKV_TPG + t;
        live[t] = tile < QKV_TILES;
        if (!live[t]) tile = QKV_TILES - 1;
        tbase[t] = tile * 16;
        const fx4* fr = (const fx4*)(F + (long)(tbase[t] + r16) * 64 + kg * 8);
        fx4 fa = fr[0], fb = fr[1], fc = fr[8], fd = fr[9];
        pack2(fa, fb, Ah0[t], Al0[t]);
        pack2(fc, fd, Ah1[t], Al1[t]);
    }
    if (isQ) {
#pragma unroll
        for (int c = 0; c < 4; c++) {
            const fx4* wr = (const fx4*)(Wq + (long)(c * 16 + r16) * 64 + kg * 8);
            fx4 wa = wr[0], wb = wr[1], wc = wr[8], wd = wr[9];
            h8v Bh0, Bl0, Bh1, Bl1;
            pack2(wa, wb, Bh0, Bl0);
            pack2(wc, wd, Bh1, Bl1);
            int ocol = c * 16 + r16;
#pragma unroll
            for (int t = 0; t < QKV_TPG; t++) {
                fx4 acc = {0.f, 0.f, 0.f, 0.f};
                MFMA6(acc, Ah0[t], Al0[t], Ah1[t], Al1[t], Bh0, Bl0, Bh1, Bl1);
                if (live[t]) {
                    long orow = tbase[t] + kg * 4;
#pragma unroll
                    for (int r = 0; r < 4; r++)
                        Q[(orow + r) * 64 + ocol] = acc[r];
                }
            }
        }
    } else {
#pragma unroll
        for (int c = 0; c < 4; c++) {
            const fx4* wrk = (const fx4*)(Wk + (long)(c * 16 + r16) * 64 + kg * 8);
            const fx4* wrv = (const fx4*)(Wv + (long)(c * 16 + r16) * 64 + kg * 8);
            fx4 ka = wrk[0], kb = wrk[1], kc = wrk[8], kd = wrk[9];
            fx4 va = wrv[0], vb = wrv[1], vc = wrv[8], vd = wrv[9];
            h8v Kh0, Kl0, Kh1, Kl1, Vh0, Vl0, Vh1, Vl1;
            pack2(ka, kb, Kh0, Kl0);
            pack2(kc, kd, Kh1, Kl1);
            pack2(va, vb, Vh0, Vl0);
            pack2(vc, vd, Vh1, Vl1);
            int ocol = c * 16 + r16;
#pragma unroll
            for (int t = 0; t < QKV_TPG; t++) {
                fx4 acck = {0.f, 0.f, 0.f, 0.f};
                fx4 accv = {0.f, 0.f, 0.f, 0.f};
                MFMA6(acck, Ah0[t], Al0[t], Ah1[t], Al1[t], Kh0, Kl0, Kh1, Kl1);
                MFMA6(accv, Ah0[t], Al0[t], Ah1[t], Al1[t], Vh0, Vl0, Vh1, Vl1);
                if (live[t]) {
                    long orow = tbase[t] + kg * 4;
#pragma unroll
                    for (int r = 0; r < 4; r++) {
                        KVh[(orow + r) * 128 + ocol] = __float2half_rn(acck[r]);
                        KVh[(orow + r) * 128 + 64 + ocol] = __float2half_rn(accv[r]);
                    }
                }
            }
        }
    }
}

// ---- fused score + softmax + aggregate (no max subtraction; scores bounded) -
// Score layout: lane = edge_slot*4 + head. Agg layout: lane = head*16 + dim.
// Writes hv in-place over Q.
// NEW this round: next-group rec0 prefetch moved from group END to the FIRST
// K-step of the current group — a full group of compute (~600cy) now covers
// its latency; previously only den-reduce+store (~100cy) did, exposing a
// ~500cy stall at every group boundary (8 boundaries per wave, ~1.5 steps
// per group on average -> boundaries are the common path).
__global__ __launch_bounds__(256) void agg_kernel(
    float* QH, const __half* __restrict__ KVh,
    const int* __restrict__ off, const ix4* __restrict__ prec) {
    __shared__ float plds[4][64];
    int lane = threadIdx.x & 63;
    int wid = threadIdx.x >> 6;
    int h = lane & 3;    // score-layout head
    int es = lane >> 2;  // score-layout edge slot
    int ha = lane >> 4;  // agg-layout head
    int g = blockIdx.x;
    int stride = gridDim.x;
    if (g >= AGG_GROUPS) return;
    int beg = off[g * 4 + wid];
    int end = off[g * 4 + wid + 1];
    ix4 rec0 = {0, 0, 0, 0};
    if (end > beg) {
        int cnt = end - beg;
        int sl = es < cnt ? es : cnt - 1;
        rec0 = prec[beg + sl];
    }
    while (true) {
        int gn = g + stride;
        bool more = gn < AGG_GROUPS;
        int nbeg = 0, nend = 0;
        if (more) {  // issue next group's offsets early
            nbeg = off[gn * 4 + wid];
            nend = off[gn * 4 + wid + 1];
        }
        int node = g * 4 + wid;
        const float4* qp = (const float4*)(QH + (long)node * 64 + h * 16);
        float4 q0 = qp[0], q1 = qp[1], q2 = qp[2], q3 = qp[3];
        float den = 0.f, acc = 0.f;
        ix4 rec = rec0;
        bool need_g_pref = more;
        for (int b = beg; b < end; b += 16) {
            int s = rec.x;
            // V gathers first: uniform SGPR row base per slot, voffset lane*2
            __half vv[16];
#pragma unroll
            for (int e = 0; e < 16; e++) {
                int se = __builtin_amdgcn_readlane(s, e * 4);
                const __half* rowp = KVh + (long)se * 128 + 64;
                vv[e] = rowp[lane];
            }
            // K fragment loads
            const float4* kp4 = (const float4*)(KVh + (long)s * 128 + h * 16);
            float4 kr0 = kp4[0], kr1 = kp4[1];
            // EARLY next-group rec0 prefetch (first step only; nbeg has landed)
            if (need_g_pref) {
                need_g_pref = false;
                if (nend > nbeg) {
                    int cnt = nend - nbeg;
                    int sl = es < cnt ? es : cnt - 1;
                    rec0 = prec[nbeg + sl];
                }
            }
            // next K-step record prefetch
            int bn = b + 16;
            ix4 recn = rec;
            if (bn < end) {
                int c2 = end - bn;
                int sl = es < c2 ? es : c2 - 1;
                recn = prec[bn + sl];
            }
            unsigned u = (h < 2) ? (unsigned)rec.y : (unsigned)rec.z;
            unsigned hw = (h & 1) ? (u >> 16) : (u & 0xffffu);
            float bias = __half2float(__ushort_as_half((unsigned short)hw));
            const __half* kh  = (const __half*)&kr0;
            const __half* kh2 = (const __half*)&kr1;
            float d0, d1;
            d0  = q0.x * (float)kh[0];   d1  = q0.y * (float)kh[1];
            d0 += q0.z * (float)kh[2];   d1 += q0.w * (float)kh[3];
            d0 += q1.x * (float)kh[4];   d1 += q1.y * (float)kh[5];
            d0 += q1.z * (float)kh[6];   d1 += q1.w * (float)kh[7];
            d0 += q2.x * (float)kh2[0];  d1 += q2.y * (float)kh2[1];
            d0 += q2.z * (float)kh2[2];  d1 += q2.w * (float)kh2[3];
            d0 += q3.x * (float)kh2[4];  d1 += q3.y * (float)kh2[5];
            d0 += q3.z * (float)kh2[6];  d1 += q3.w * (float)kh2[7];
            float sc = (d0 + d1) * 0.25f + bias;
            bool valid = (b + es) < end;
            float p = valid ? __expf(sc) : 0.f;  // no max: scores bounded ~|10|
            den += p;
            plds[wid][lane] = p;
            asm volatile("s_waitcnt lgkmcnt(0)" ::: "memory");
            float a0 = 0.f, a1 = 0.f, a2 = 0.f, a3 = 0.f;
#pragma unroll
            for (int e = 0; e < 16; e += 4) {
                a0 += plds[wid][(e + 0) * 4 + ha] * (float)vv[e + 0];
                a1 += plds[wid][(e + 1) * 4 + ha] * (float)vv[e + 1];
                a2 += plds[wid][(e + 2) * 4 + ha] * (float)vv[e + 2];
                a3 += plds[wid][(e + 3) * 4 + ha] * (float)vv[e + 3];
            }
            acc += (a0 + a1) + (a2 + a3);
            rec = recn;
        }
        if (need_g_pref && nend > nbeg) {  // current group was empty
            int cnt = nend - nbeg;
            int sl = es < cnt ? es : cnt - 1;
            rec0 = prec[nbeg + sl];
        }
        den += __shfl_xor(den, 4, 64);
        den += __shfl_xor(den, 8, 64);
        den += __shfl_xor(den, 16, 64);
        den += __shfl_xor(den, 32, 64);
        float denA = __shfl(den, ha, 64);
        float hv = (denA > 0.f) ? acc / denA : 0.f;
        QH[(long)node * 64 + lane] = hv;
        if (!more) break;
        g = gn;
        beg = nbeg;
        end = nend;
    }
}

// ---- output projection via MFMA: out = H @ Wo.T + bo -----------------------
__global__ __launch_bounds__(256) void oproj_kernel(
    const float* __restrict__ H, const float* __restrict__ Wo,
    const float* __restrict__ bo, float* __restrict__ out) {
    int lane = threadIdx.x & 63;
    int wid = threadIdx.x >> 6;
    int wave = blockIdx.x * 4 + wid;
    if (wave >= OP_GROUPS) return;
    int r16 = lane & 15;
    int kg = lane >> 4;
    h8v Ah0[QKV_TPG], Al0[QKV_TPG], Ah1[QKV_TPG], Al1[QKV_TPG];
    int tbase[QKV_TPG];
    bool live[QKV_TPG];
#pragma unroll
    for (int t = 0; t < QKV_TPG; t++) {
        int tile = wave * QKV_TPG + t;
        live[t] = tile < QKV_TILES;
        if (!live[t]) tile = QKV_TILES - 1;
        tbase[t] = tile * 16;
        const fx4* fr = (const fx4*)(H + (long)(tbase[t] + r16) * 64 + kg * 8);
        fx4 fa = fr[0], fb = fr[1], fc = fr[8], fd = fr[9];
        pack2(fa, fb, Ah0[t], Al0[t]);
        pack2(fc, fd, Ah1[t], Al1[t]);
    }
#pragma unroll
    for (int c = 0; c < 4; c++) {
        const fx4* wr = (const fx4*)(Wo + (long)(c * 16 + r16) * 64 + kg * 8);
        fx4 wa = wr[0], wb = wr[1], wc = wr[8], wd = wr[9];
        h8v Bh0, Bl0, Bh1, Bl1;
        pack2(wa, wb, Bh0, Bl0);
        pack2(wc, wd, Bh1, Bl1);
        int ocol = c * 16 + r16;
        float bias = bo[ocol];
#pragma unroll
        for (int t = 0; t < QKV_TPG; t++) {
            fx4 acc = {bias, bias, bias, bias};
            MFMA6(acc, Ah0[t], Al0[t], Ah1[t], Al1[t], Bh0, Bl0, Bh1, Bl1);
            if (live[t]) {
                long orow = tbase[t] + kg * 4;
#pragma unroll
                for (int r = 0; r < 4; r++)
                    out[(orow + r) * 64 + ocol] = acc[r];
            }
        }
    }
}

extern "C" void kernel_launch(void* const* d_in, const int* in_sizes, int n_in,
                              void* d_out, int out_size, void* d_ws, size_t ws_size,
                              hipStream_t stream) {
    const float* src_feat  = (const float*)d_in[0];
    const float* dst_feat  = (const float*)d_in[1];
    const float* edge_feat = (const float*)d_in[2];
    const int*   src_idx   = (const int*)d_in[3];
    const int*   dst_idx   = (const int*)d_in[4];
    const float* Wq        = (const float*)d_in[5];
    const float* Wk        = (const float*)d_in[6];
    const float* Wv        = (const float*)d_in[7];
    const float* We        = (const float*)d_in[8];
    const float* be        = (const float*)d_in[9];
    const float* Wo        = (const float*)d_in[10];
    const float* bo        = (const float*)d_in[11];
    float* out = (float*)d_out;

    // ws layout
    float*  Q    = (float*)d_ws;                          // N*64 f (also hv out)
    __half* KVh  = (__half*)(Q + (size_t)N_NODES * 64);   // N*128 h
    ix4*    prec = (ix4*)(KVh + (size_t)N_NODES * 128);   // E recs (16B)
    int*    off  = (int*)(prec + (size_t)N_EDGES);        // N+1
    int*    bsum = off + (N_NODES + 1);                   // NB
    // rank[E] aliases Q's buffer: consumed by scatter BEFORE qkv writes Q.
    int*    rank = (int*)Q;

    (void)hipMemsetAsync(off, 0, (N_NODES + 1) * sizeof(int), stream);
    hist_kernel<<<(N_EDGES / 4 + 255) / 256, 256, 0, stream>>>(dst_idx, off, rank);
    scanA_kernel<<<NB, 256, 0, stream>>>(off, bsum);
    scanC_kernel<<<NB, 256, 0, stream>>>(off, bsum);
    scatter_kernel<<<SCAT4_BLOCKS, 256, 0, stream>>>(
        src_idx, dst_idx, rank, edge_feat, We, be, off, prec);
    qkv_kernel<<<(QKV_WAVES + 3) / 4, 256, 0, stream>>>(
        dst_feat, src_feat, Wq, Wk, Wv, Q, KVh);
    agg_kernel<<<AGG_BLOCKS, 256, 0, stream>>>(Q, KVh, off, prec);
    oproj_kernel<<<(OP_GROUPS + 3) / 4, 256, 0, stream>>>(Q, Wo, bo, out);
}

// Round 14
// 269.009 us; speedup vs baseline: 1.1979x; 1.1979x over previous
//
#include <hip/hip_runtime.h>
#include <hip/hip_fp16.h>
#include <math.h>

#define N_NODES 100000
#define N_EDGES 1600000
#define NH 4
#define HD 16
#define NB 98             // ceil(100000/1024) scan blocks
#define AGG_GROUPS 25000  // N_NODES/4
#define AGG_BLOCKS 3125   // 8 groups per block exactly (no ragged tail)
#define SCAT_BLOCKS 1563  // ceil(1.6M / 1024); 4 wave-strided edges per thread
#define QKV_TILES 6250    // 100000/16 node-tiles
#define QKV_TPG 4         // tiles per wave
#define QKV_GROUPS 1563   // ceil(6250/4)
#define QKV_WAVES (2 * QKV_GROUPS)  // Q-groups + fused-KV-groups
#define OP_GROUPS 1563    // oproj wave-groups (4 tiles each)

typedef float fx4 __attribute__((ext_vector_type(4)));
typedef int   ix4 __attribute__((ext_vector_type(4)));
typedef _Float16 h8v __attribute__((ext_vector_type(8)));

// ---- CSR build -------------------------------------------------------------

// off[] must be zeroed (hipMemsetAsync) before this.
// Saves each edge's within-node arrival rank so scatter needs NO atomic.
__global__ void hist_kernel(const int* __restrict__ dst_idx, int* __restrict__ off,
                            int* __restrict__ rank) {
    int tid = blockIdx.x * blockDim.x + threadIdx.x;
    int base = tid * 4;
    if (base + 3 < N_EDGES) {
        int4 d = ((const int4*)dst_idx)[tid];  // cached: dst_idx reused by scatter
        int4 r;
        r.x = atomicAdd(&off[d.x], 1);
        r.y = atomicAdd(&off[d.y], 1);
        r.z = atomicAdd(&off[d.z], 1);
        r.w = atomicAdd(&off[d.w], 1);
        ((int4*)rank)[tid] = r;
    } else {
        for (int j = base; j < N_EDGES; j++)
            if (j < N_EDGES) rank[j] = atomicAdd(&off[dst_idx[j]], 1);
    }
}

// per-block sums of 1024-element chunks
__global__ void scanA_kernel(const int* __restrict__ off, int* __restrict__ bsum) {
    __shared__ int s[256];
    int t = threadIdx.x;
    int base = blockIdx.x * 1024 + t * 4;
    int v = 0;
#pragma unroll
    for (int j = 0; j < 4; j++) {
        int idx = base + j;
        if (idx < N_NODES) v += off[idx];
    }
    s[t] = v;
    __syncthreads();
    for (int o = 128; o > 0; o >>= 1) {
        if (t < o) s[t] += s[t + o];
        __syncthreads();
    }
    if (t == 0) bsum[blockIdx.x] = s[0];
}

// in-place exclusive scan of counts -> offsets (scanB folded in).
__global__ void scanC_kernel(int* __restrict__ off, const int* __restrict__ bsum) {
    __shared__ int sb[NB];
    __shared__ int s[256];
    int t = threadIdx.x;
    if (t < NB) sb[t] = bsum[t];
    __syncthreads();
    int pre = 0, tot = 0;
    int myb = (int)blockIdx.x;
    for (int b = 0; b < NB; b++) {
        int x = sb[b];
        if (b < myb) pre += x;
        tot += x;
    }
    int base = myb * 1024 + t * 4;
    int v[4];
    int tsum = 0;
#pragma unroll
    for (int j = 0; j < 4; j++) {
        int idx = base + j;
        v[j] = (idx < N_NODES) ? off[idx] : 0;
        tsum += v[j];
    }
    s[t] = tsum;
    __syncthreads();
    for (int o = 1; o < 256; o <<= 1) {
        int x = (t >= o) ? s[t - o] : 0;
        __syncthreads();
        s[t] += x;
        __syncthreads();
    }
    int excl = s[t] - tsum + pre;
#pragma unroll
    for (int j = 0; j < 4; j++) {
        int idx = base + j;
        if (idx < N_NODES) {
            off[idx] = excl;
            excl += v[j];
        }
    }
    if (myb == 0 && t == 0) off[N_NODES] = tot;
}

// scatter edges into dst-grouped order; ONE packed 16B record per edge:
// {src, bias(h0,h1) fp16x2, bias(h2,h3) fp16x2, pad}
// Atomic-free; plain cached prec store (R7: NT here hurts agg).
// 4 edges per thread, WAVE-STRIDED (e = blk*1024 + j*256 + tid): every
// j-slice keeps the fully-coalesced lane->row mapping (R13's tid*4 blocking
// broke coalescing, FETCH 60->240 MB), while 4 independent random stores
// per thread raise store-level parallelism.
__global__ void scatter_kernel(const int* __restrict__ src_idx,
                               const int* __restrict__ dst_idx,
                               const int* __restrict__ rank,
                               const float* __restrict__ edge_feat,
                               const float* __restrict__ We,
                               const float* __restrict__ be,
                               const int* __restrict__ off,
                               ix4* __restrict__ prec) {
    int tid = threadIdx.x;
    long base = (long)blockIdx.x * 1024;
    int ev[4], dv[4], sv[4], rv[4];
    bool val[4];
#pragma unroll
    for (int j = 0; j < 4; j++) {
        long e = base + j * 256 + tid;
        val[j] = e < N_EDGES;
        ev[j] = val[j] ? (int)e : 0;
        dv[j] = val[j] ? dst_idx[ev[j]] : 0;
        sv[j] = val[j] ? src_idx[ev[j]] : 0;
        rv[j] = val[j] ? rank[ev[j]] : 0;
    }
    fx4 ef[4][4];
#pragma unroll
    for (int j = 0; j < 4; j++) {
        const fx4* ep = (const fx4*)(edge_feat + (long)ev[j] * 16);
        ef[j][0] = __builtin_nontemporal_load(ep);      // true streaming
        ef[j][1] = __builtin_nontemporal_load(ep + 1);
        ef[j][2] = __builtin_nontemporal_load(ep + 2);
        ef[j][3] = __builtin_nontemporal_load(ep + 3);
    }
    int pos[4];
#pragma unroll
    for (int j = 0; j < 4; j++) pos[j] = off[dv[j]] + rv[j];
#pragma unroll
    for (int j = 0; j < 4; j++) {
        float bp[4];
#pragma unroll
        for (int h = 0; h < NH; h++) {
            const float4* wp = (const float4*)(We + h * 16);
            float4 w0 = wp[0], w1 = wp[1], w2 = wp[2], w3 = wp[3];
            float acc = be[h];
            acc += ef[j][0][0]*w0.x + ef[j][0][1]*w0.y + ef[j][0][2]*w0.z + ef[j][0][3]*w0.w;
            acc += ef[j][1][0]*w1.x + ef[j][1][1]*w1.y + ef[j][1][2]*w1.z + ef[j][1][3]*w1.w;
            acc += ef[j][2][0]*w2.x + ef[j][2][1]*w2.y + ef[j][2][2]*w2.z + ef[j][2][3]*w2.w;
            acc += ef[j][3][0]*w3.x + ef[j][3][1]*w3.y + ef[j][3][2]*w3.z + ef[j][3][3]*w3.w;
            bp[h] = acc;
        }
        __half2 b01 = __halves2half2(__float2half_rn(bp[0]), __float2half_rn(bp[1]));
        __half2 b23 = __halves2half2(__float2half_rn(bp[2]), __float2half_rn(bp[3]));
        ix4 rec;
        rec.x = sv[j];
        rec.y = __builtin_bit_cast(int, b01);
        rec.z = __builtin_bit_cast(int, b23);
        rec.w = 0;
        if (val[j]) prec[pos[j]] = rec;
    }
}

// ---- QKV projections via MFMA (fp16 hi/lo split = fp32-accurate) -----------
// A-frag: row=lane&15, k=(lane>>4)*8+j (contiguous from row-major feat).
// B-frag: col=lane&15, same k (contiguous from row-major W: need W[col][k]).
// D: col=lane&15, row=(lane>>4)*4+r.  (verified R5-R13, absmax unchanged)
// Split precision: x = hi + lo (fp16); D = Ah*Bh + Al*Bh + Ah*Bl, fp32 acc.
// 4 tiles per wave (B packed ONCE per 4 tiles); K+V fused in one wave.
__device__ __forceinline__ void pack2(fx4 a, fx4 b, h8v& hi, h8v& lo) {
#pragma unroll
    for (int j = 0; j < 4; j++) {
        float xa = a[j], xb = b[j];
        _Float16 ha = (_Float16)xa, hb = (_Float16)xb;
        hi[j] = ha;
        hi[j + 4] = hb;
        lo[j] = (_Float16)(xa - (float)ha);
        lo[j + 4] = (_Float16)(xb - (float)hb);
    }
}

#define MFMA6(ACC, AH0, AL0, AH1, AL1, BH0, BL0, BH1, BL1)                      \
    ACC = __builtin_amdgcn_mfma_f32_16x16x32_f16(AH0, BH0, ACC, 0, 0, 0);       \
    ACC = __builtin_amdgcn_mfma_f32_16x16x32_f16(AL0, BH0, ACC, 0, 0, 0);       \
    ACC = __builtin_amdgcn_mfma_f32_16x16x32_f16(AH0, BL0, ACC, 0, 0, 0);       \
    ACC = __builtin_amdgcn_mfma_f32_16x16x32_f16(AH1, BH1, ACC, 0, 0, 0);       \
    ACC = __builtin_amdgcn_mfma_f32_16x16x32_f16(AL1, BH1, ACC, 0, 0, 0);       \
    ACC = __builtin_amdgcn_mfma_f32_16x16x32_f16(AH1, BL1, ACC, 0, 0, 0);

__global__ __launch_bounds__(256) void qkv_kernel(
    const float* __restrict__ dst_feat, const float* __restrict__ src_feat,
    const float* __restrict__ Wq, const float* __restrict__ Wk,
    const float* __restrict__ Wv,
    float* __restrict__ Q, __half* __restrict__ KVh) {
    int lane = threadIdx.x & 63;
    int wid = threadIdx.x >> 6;
    int wave = blockIdx.x * 4 + wid;
    if (wave >= QKV_WAVES) return;
    bool isQ = wave < QKV_GROUPS;
    int tg = isQ ? wave : wave - QKV_GROUPS;
    const float* F = isQ ? dst_feat : src_feat;
    int r16 = lane & 15;
    int kg = lane >> 4;
    h8v Ah0[QKV_TPG], Al0[QKV_TPG], Ah1[QKV_TPG], Al1[QKV_TPG];
    int tbase[QKV_TPG];
    bool live[QKV_TPG];
#pragma unroll
    for (int t = 0; t < QKV_TPG; t++) {
        int tile = tg * QKV_TPG + t;
        live[t] = tile < QKV_TILES;
        if (!live[t]) tile = QKV_TILES - 1;
        tbase[t] = tile * 16;
        const fx4* fr = (const fx4*)(F + (long)(tbase[t] + r16) * 64 + kg * 8);
        fx4 fa = fr[0], fb = fr[1], fc = fr[8], fd = fr[9];
        pack2(fa, fb, Ah0[t], Al0[t]);
        pack2(fc, fd, Ah1[t], Al1[t]);
    }
    if (isQ) {
#pragma unroll
        for (int c = 0; c < 4; c++) {
            const fx4* wr = (const fx4*)(Wq + (long)(c * 16 + r16) * 64 + kg * 8);
            fx4 wa = wr[0], wb = wr[1], wc = wr[8], wd = wr[9];
            h8v Bh0, Bl0, Bh1, Bl1;
            pack2(wa, wb, Bh0, Bl0);
            pack2(wc, wd, Bh1, Bl1);
            int ocol = c * 16 + r16;
#pragma unroll
            for (int t = 0; t < QKV_TPG; t++) {
                fx4 acc = {0.f, 0.f, 0.f, 0.f};
                MFMA6(acc, Ah0[t], Al0[t], Ah1[t], Al1[t], Bh0, Bl0, Bh1, Bl1);
                if (live[t]) {
                    long orow = tbase[t] + kg * 4;
#pragma unroll
                    for (int r = 0; r < 4; r++)
                        Q[(orow + r) * 64 + ocol] = acc[r];
                }
            }
        }
    } else {
#pragma unroll
        for (int c = 0; c < 4; c++) {
            const fx4* wrk = (const fx4*)(Wk + (long)(c * 16 + r16) * 64 + kg * 8);
            const fx4* wrv = (const fx4*)(Wv + (long)(c * 16 + r16) * 64 + kg * 8);
            fx4 ka = wrk[0], kb = wrk[1], kc = wrk[8], kd = wrk[9];
            fx4 va = wrv[0], vb = wrv[1], vc = wrv[8], vd = wrv[9];
            h8v Kh0, Kl0, Kh1, Kl1, Vh0, Vl0, Vh1, Vl1;
            pack2(ka, kb, Kh0, Kl0);
            pack2(kc, kd, Kh1, Kl1);
            pack2(va, vb, Vh0, Vl0);
            pack2(vc, vd, Vh1, Vl1);
            int ocol = c * 16 + r16;
#pragma unroll
            for (int t = 0; t < QKV_TPG; t++) {
                fx4 acck = {0.f, 0.f, 0.f, 0.f};
                fx4 accv = {0.f, 0.f, 0.f, 0.f};
                MFMA6(acck, Ah0[t], Al0[t], Ah1[t], Al1[t], Kh0, Kl0, Kh1, Kl1);
                MFMA6(accv, Ah0[t], Al0[t], Ah1[t], Al1[t], Vh0, Vl0, Vh1, Vl1);
                if (live[t]) {
                    long orow = tbase[t] + kg * 4;
#pragma unroll
                    for (int r = 0; r < 4; r++) {
                        KVh[(orow + r) * 128 + ocol] = __float2half_rn(acck[r]);
                        KVh[(orow + r) * 128 + 64 + ocol] = __float2half_rn(accv[r]);
                    }
                }
            }
        }
    }
}

// ---- fused score + softmax + aggregate (no max subtraction; scores bounded) -
// Score layout: lane = edge_slot*4 + head. Agg layout: lane = head*16 + dim.
// Writes hv in-place over Q. Early next-group rec0 prefetch in first K-step
// (R13: measured neutral, kept — helps tail-degree distributions at no cost).
__global__ __launch_bounds__(256) void agg_kernel(
    float* QH, const __half* __restrict__ KVh,
    const int* __restrict__ off, const ix4* __restrict__ prec) {
    __shared__ float plds[4][64];
    int lane = threadIdx.x & 63;
    int wid = threadIdx.x >> 6;
    int h = lane & 3;    // score-layout head
    int es = lane >> 2;  // score-layout edge slot
    int ha = lane >> 4;  // agg-layout head
    int g = blockIdx.x;
    int stride = gridDim.x;
    if (g >= AGG_GROUPS) return;
    int beg = off[g * 4 + wid];
    int end = off[g * 4 + wid + 1];
    ix4 rec0 = {0, 0, 0, 0};
    if (end > beg) {
        int cnt = end - beg;
        int sl = es < cnt ? es : cnt - 1;
        rec0 = prec[beg + sl];
    }
    while (true) {
        int gn = g + stride;
        bool more = gn < AGG_GROUPS;
        int nbeg = 0, nend = 0;
        if (more) {  // issue next group's offsets early
            nbeg = off[gn * 4 + wid];
            nend = off[gn * 4 + wid + 1];
        }
        int node = g * 4 + wid;
        const float4* qp = (const float4*)(QH + (long)node * 64 + h * 16);
        float4 q0 = qp[0], q1 = qp[1], q2 = qp[2], q3 = qp[3];
        float den = 0.f, acc = 0.f;
        ix4 rec = rec0;
        bool need_g_pref = more;
        for (int b = beg; b < end; b += 16) {
            int s = rec.x;
            __half vv[16];
#pragma unroll
            for (int e = 0; e < 16; e++) {
                int se = __builtin_amdgcn_readlane(s, e * 4);
                const __half* rowp = KVh + (long)se * 128 + 64;
                vv[e] = rowp[lane];
            }
            const float4* kp4 = (const float4*)(KVh + (long)s * 128 + h * 16);
            float4 kr0 = kp4[0], kr1 = kp4[1];
            if (need_g_pref) {  // early next-group rec0 prefetch
                need_g_pref = false;
                if (nend > nbeg) {
                    int cnt = nend - nbeg;
                    int sl = es < cnt ? es : cnt - 1;
                    rec0 = prec[nbeg + sl];
                }
            }
            int bn = b + 16;
            ix4 recn = rec;
            if (bn < end) {  // next K-step record prefetch
                int c2 = end - bn;
                int sl = es < c2 ? es : c2 - 1;
                recn = prec[bn + sl];
            }
            unsigned u = (h < 2) ? (unsigned)rec.y : (unsigned)rec.z;
            unsigned hw = (h & 1) ? (u >> 16) : (u & 0xffffu);
            float bias = __half2float(__ushort_as_half((unsigned short)hw));
            const __half* kh  = (const __half*)&kr0;
            const __half* kh2 = (const __half*)&kr1;
            float d0, d1;
            d0  = q0.x * (float)kh[0];   d1  = q0.y * (float)kh[1];
            d0 += q0.z * (float)kh[2];   d1 += q0.w * (float)kh[3];
            d0 += q1.x * (float)kh[4];   d1 += q1.y * (float)kh[5];
            d0 += q1.z * (float)kh[6];   d1 += q1.w * (float)kh[7];
            d0 += q2.x * (float)kh2[0];  d1 += q2.y * (float)kh2[1];
            d0 += q2.z * (float)kh2[2];  d1 += q2.w * (float)kh2[3];
            d0 += q3.x * (float)kh2[4];  d1 += q3.y * (float)kh2[5];
            d0 += q3.z * (float)kh2[6];  d1 += q3.w * (float)kh2[7];
            float sc = (d0 + d1) * 0.25f + bias;
            bool valid = (b + es) < end;
            float p = valid ? __expf(sc) : 0.f;  // no max: scores bounded ~|10|
            den += p;
            plds[wid][lane] = p;
            asm volatile("s_waitcnt lgkmcnt(0)" ::: "memory");
            float a0 = 0.f, a1 = 0.f, a2 = 0.f, a3 = 0.f;
#pragma unroll
            for (int e = 0; e < 16; e += 4) {
                a0 += plds[wid][(e + 0) * 4 + ha] * (float)vv[e + 0];
                a1 += plds[wid][(e + 1) * 4 + ha] * (float)vv[e + 1];
                a2 += plds[wid][(e + 2) * 4 + ha] * (float)vv[e + 2];
                a3 += plds[wid][(e + 3) * 4 + ha] * (float)vv[e + 3];
            }
            acc += (a0 + a1) + (a2 + a3);
            rec = recn;
        }
        if (need_g_pref && nend > nbeg) {  // current group was empty
            int cnt = nend - nbeg;
            int sl = es < cnt ? es : cnt - 1;
            rec0 = prec[nbeg + sl];
        }
        den += __shfl_xor(den, 4, 64);
        den += __shfl_xor(den, 8, 64);
        den += __shfl_xor(den, 16, 64);
        den += __shfl_xor(den, 32, 64);
        float denA = __shfl(den, ha, 64);
        float hv = (denA > 0.f) ? acc / denA : 0.f;
        QH[(long)node * 64 + lane] = hv;
        if (!more) break;
        g = gn;
        beg = nbeg;
        end = nend;
    }
}

// ---- output projection via MFMA: out = H @ Wo.T + bo -----------------------
__global__ __launch_bounds__(256) void oproj_kernel(
    const float* __restrict__ H, const float* __restrict__ Wo,
    const float* __restrict__ bo, float* __restrict__ out) {
    int lane = threadIdx.x & 63;
    int wid = threadIdx.x >> 6;
    int wave = blockIdx.x * 4 + wid;
    if (wave >= OP_GROUPS) return;
    int r16 = lane & 15;
    int kg = lane >> 4;
    h8v Ah0[QKV_TPG], Al0[QKV_TPG], Ah1[QKV_TPG], Al1[QKV_TPG];
    int tbase[QKV_TPG];
    bool live[QKV_TPG];
#pragma unroll
    for (int t = 0; t < QKV_TPG; t++) {
        int tile = wave * QKV_TPG + t;
        live[t] = tile < QKV_TILES;
        if (!live[t]) tile = QKV_TILES - 1;
        tbase[t] = tile * 16;
        const fx4* fr = (const fx4*)(H + (long)(tbase[t] + r16) * 64 + kg * 8);
        fx4 fa = fr[0], fb = fr[1], fc = fr[8], fd = fr[9];
        pack2(fa, fb, Ah0[t], Al0[t]);
        pack2(fc, fd, Ah1[t], Al1[t]);
    }
#pragma unroll
    for (int c = 0; c < 4; c++) {
        const fx4* wr = (const fx4*)(Wo + (long)(c * 16 + r16) * 64 + kg * 8);
        fx4 wa = wr[0], wb = wr[1], wc = wr[8], wd = wr[9];
        h8v Bh0, Bl0, Bh1, Bl1;
        pack2(wa, wb, Bh0, Bl0);
        pack2(wc, wd, Bh1, Bl1);
        int ocol = c * 16 + r16;
        float bias = bo[ocol];
#pragma unroll
        for (int t = 0; t < QKV_TPG; t++) {
            fx4 acc = {bias, bias, bias, bias};
            MFMA6(acc, Ah0[t], Al0[t], Ah1[t], Al1[t], Bh0, Bl0, Bh1, Bl1);
            if (live[t]) {
                long orow = tbase[t] + kg * 4;
#pragma unroll
                for (int r = 0; r < 4; r++)
                    out[(orow + r) * 64 + ocol] = acc[r];
            }
        }
    }
}

extern "C" void kernel_launch(void* const* d_in, const int* in_sizes, int n_in,
                              void* d_out, int out_size, void* d_ws, size_t ws_size,
                              hipStream_t stream) {
    const float* src_feat  = (const float*)d_in[0];
    const float* dst_feat  = (const float*)d_in[1];
    const float* edge_feat = (const float*)d_in[2];
    const int*   src_idx   = (const int*)d_in[3];
    const int*   dst_idx   = (const int*)d_in[4];
    const float* Wq        = (const float*)d_in[5];
    const float* Wk        = (const float*)d_in[6];
    const float* Wv        = (const float*)d_in[7];
    const float* We        = (const float*)d_in[8];
    const float* be        = (const float*)d_in[9];
    const float* Wo        = (const float*)d_in[10];
    const float* bo        = (const float*)d_in[11];
    float* out = (float*)d_out;

    // ws layout
    float*  Q    = (float*)d_ws;                          // N*64 f (also hv out)
    __half* KVh  = (__half*)(Q + (size_t)N_NODES * 64);   // N*128 h
    ix4*    prec = (ix4*)(KVh + (size_t)N_NODES * 128);   // E recs (16B)
    int*    off  = (int*)(prec + (size_t)N_EDGES);        // N+1
    int*    bsum = off + (N_NODES + 1);                   // NB
    // rank[E] aliases Q's buffer: consumed by scatter BEFORE qkv writes Q.
    int*    rank = (int*)Q;

    (void)hipMemsetAsync(off, 0, (N_NODES + 1) * sizeof(int), stream);
    hist_kernel<<<(N_EDGES / 4 + 255) / 256, 256, 0, stream>>>(dst_idx, off, rank);
    scanA_kernel<<<NB, 256, 0, stream>>>(off, bsum);
    scanC_kernel<<<NB, 256, 0, stream>>>(off, bsum);
    scatter_kernel<<<SCAT_BLOCKS, 256, 0, stream>>>(
        src_idx, dst_idx, rank, edge_feat, We, be, off, prec);
    qkv_kernel<<<(QKV_WAVES + 3) / 4, 256, 0, stream>>>(
        dst_feat, src_feat, Wq, Wk, Wv, Q, KVh);
    agg_kernel<<<AGG_BLOCKS, 256, 0, stream>>>(Q, KVh, off, prec);
    oproj_kernel<<<(OP_GROUPS + 3) / 4, 256, 0, stream>>>(Q, Wo, bo, out);
}